// Round 2
// baseline (171.468 us; speedup 1.0000x reference)
//
#include <hip/hip_runtime.h>
#include <math.h>

// Parallel NeRF via wave-level scan of rigid transforms.
// One 64-lane wave per chain (4 chains per 256-thread block, no __syncthreads,
// no LDS). Lane owns 8 residues (24 atoms): serial compose -> shfl-up scan
// (6 levels) -> replay with exclusive prefix.
//
// Delta transform (closed form, frame of previous triple):
//   u = (-cos th, cos ta sin th, sin ta sin th)
//   R = [u | (-sin th, -cos th cos ta, -cos th sin ta) | (0, -sin ta, cos ta)]
//   t = L * u
// compose-with-delta exploits the zero + 2-term structure of cols 1/2 and
// t_new = t + L * newcol0 (~31 FMA vs 45 for general compose).

#define LCH 512
#define NRES 511
#define RPL 8   // residues per lane (64*8 = 512 >= 511)

struct Xf { float r[9]; float t[3]; };

__device__ __forceinline__ Xf xf_compose(const Xf& A, const Xf& B) {
  Xf C;
#pragma unroll
  for (int i = 0; i < 3; ++i) {
    float a0 = A.r[3*i+0], a1 = A.r[3*i+1], a2 = A.r[3*i+2];
    C.r[3*i+0] = a0*B.r[0] + a1*B.r[3] + a2*B.r[6];
    C.r[3*i+1] = a0*B.r[1] + a1*B.r[4] + a2*B.r[7];
    C.r[3*i+2] = a0*B.r[2] + a1*B.r[5] + a2*B.r[8];
    C.t[i]     = a0*B.t[0] + a1*B.t[1] + a2*B.t[2] + A.t[i];
  }
  return C;
}

// P := P o Delta(theta, len, tau), sparsity-aware.
__device__ __forceinline__ void xf_step(Xf& P, float theta, float len, float tau) {
  float st, ct, sx, cx;
  __sincosf(theta, &st, &ct);
  __sincosf(tau, &sx, &cx);
  float ux = -ct, uy = cx*st, uz = sx*st;      // delta col0 (= d_local / L)
  float v0 = -st, v1 = -ct*cx, v2 = -ct*sx;    // delta col1
  // delta col2 = (0, -sx, cx)
  float c00 = P.r[0]*ux + P.r[1]*uy + P.r[2]*uz;
  float c10 = P.r[3]*ux + P.r[4]*uy + P.r[5]*uz;
  float c20 = P.r[6]*ux + P.r[7]*uy + P.r[8]*uz;
  float c01 = P.r[0]*v0 + P.r[1]*v1 + P.r[2]*v2;
  float c11 = P.r[3]*v0 + P.r[4]*v1 + P.r[5]*v2;
  float c21 = P.r[6]*v0 + P.r[7]*v1 + P.r[8]*v2;
  float c02 = P.r[2]*cx - P.r[1]*sx;
  float c12 = P.r[5]*cx - P.r[4]*sx;
  float c22 = P.r[8]*cx - P.r[7]*sx;
  P.t[0] += len*c00; P.t[1] += len*c10; P.t[2] += len*c20;
  P.r[0]=c00; P.r[1]=c01; P.r[2]=c02;
  P.r[3]=c10; P.r[4]=c11; P.r[5]=c12;
  P.r[6]=c20; P.r[7]=c21; P.r[8]=c22;
}

// P := Delta(theta, len, tau)  (first atom of a lane, skips identity compose)
__device__ __forceinline__ void xf_set_delta(Xf& P, float theta, float len, float tau) {
  float st, ct, sx, cx;
  __sincosf(theta, &st, &ct);
  __sincosf(tau, &sx, &cx);
  float ux = -ct, uy = cx*st, uz = sx*st;
  P.r[0]=ux; P.r[1]=-st;    P.r[2]=0.f;
  P.r[3]=uy; P.r[4]=-ct*cx; P.r[5]=-sx;
  P.r[6]=uz; P.r[7]=-ct*sx; P.r[8]=cx;
  P.t[0]=len*ux; P.t[1]=len*uy; P.t[2]=len*uz;
}

__device__ __forceinline__ Xf xf_shfl_up(const Xf& P, int d) {
  Xf O;
#pragma unroll
  for (int i = 0; i < 9; ++i) O.r[i] = __shfl_up(P.r[i], d, 64);
#pragma unroll
  for (int i = 0; i < 3; ++i) O.t[i] = __shfl_up(P.t[i], d, 64);
  return O;
}

static __device__ const float c_init[9] = {
  17.047f, 14.099f, 3.625f,
  16.967f, 12.784f, 4.338f,
  15.685f, 12.755f, 5.133f };

__global__ __launch_bounds__(256) void nerf_wavescan_kernel(
    const float* __restrict__ g_phi, const float* __restrict__ g_psi,
    const float* __restrict__ g_omg, const float* __restrict__ g_bl,
    const float* __restrict__ g_ba, float* __restrict__ g_out)
{
  const int lane  = threadIdx.x & 63;
  const int wave  = threadIdx.x >> 6;
  const int chain = blockIdx.x * 4 + wave;

  const float* phir = g_phi + (size_t)chain * LCH;
  const float* psir = g_psi + (size_t)chain * LCH;
  const float* omgr = g_omg + (size_t)chain * LCH;
  const float* blr  = g_bl  + (size_t)chain * LCH * 3;
  const float* bar  = g_ba  + (size_t)chain * LCH * 3;

  const int j0 = lane * RPL;  // first residue of this lane

  // ---- vectorized input loads (all 16B-aligned) ----
  float psi_[RPL], omg_[RPL], phl_[RPL];  // phl_[e] = phi[j0+e] (aligned)
  float bl_[3*RPL], ba_[3*RPL];
  {
    const float4* p;
    p = (const float4*)(psir + j0);
#pragma unroll
    for (int q = 0; q < RPL/4; ++q) { float4 v = p[q];
      psi_[4*q]=v.x; psi_[4*q+1]=v.y; psi_[4*q+2]=v.z; psi_[4*q+3]=v.w; }
    p = (const float4*)(omgr + j0);
#pragma unroll
    for (int q = 0; q < RPL/4; ++q) { float4 v = p[q];
      omg_[4*q]=v.x; omg_[4*q+1]=v.y; omg_[4*q+2]=v.z; omg_[4*q+3]=v.w; }
    p = (const float4*)(phir + j0);
#pragma unroll
    for (int q = 0; q < RPL/4; ++q) { float4 v = p[q];
      phl_[4*q]=v.x; phl_[4*q+1]=v.y; phl_[4*q+2]=v.z; phl_[4*q+3]=v.w; }
    p = (const float4*)(blr + (size_t)j0*3);
#pragma unroll
    for (int q = 0; q < (3*RPL)/4; ++q) { float4 v = p[q];
      bl_[4*q]=v.x; bl_[4*q+1]=v.y; bl_[4*q+2]=v.z; bl_[4*q+3]=v.w; }
    p = (const float4*)(bar + (size_t)j0*3);
#pragma unroll
    for (int q = 0; q < (3*RPL)/4; ++q) { float4 v = p[q];
      ba_[4*q]=v.x; ba_[4*q+1]=v.y; ba_[4*q+2]=v.z; ba_[4*q+3]=v.w; }
  }
  // phi[j+1] for e=0..6 is phl_[e+1]; for e=7 it's next lane's phl_[0].
  float phi_next = __shfl_down(phl_[0], 1, 64);  // = phi[j0+8] (lanes 0..62)
  float phiN[RPL];
#pragma unroll
  for (int e = 0; e < RPL-1; ++e) phiN[e] = phl_[e+1];
  phiN[RPL-1] = phi_next;  // lane 63 never uses e=7 (j=511 >= NRES)

  // ---- Phase A: serial product of this lane's deltas ----
  Xf P;
  xf_set_delta(P, ba_[1], bl_[2], psi_[0]);          // residue j0, atom N
  xf_step(P, ba_[2], bl_[0], omg_[0]);               // CA
  xf_step(P, ba_[0], bl_[1], phiN[0]);               // C
#pragma unroll
  for (int e = 1; e < RPL; ++e) {
    if (j0 + e < NRES) {
      xf_step(P, ba_[3*e+1], bl_[3*e+2], psi_[e]);
      xf_step(P, ba_[3*e+2], bl_[3*e+0], omg_[e]);
      xf_step(P, ba_[3*e+0], bl_[3*e+1], phiN[e]);
    }
  }

  // ---- Phase B: wave inclusive scan (non-commutative, earlier on left) ----
#pragma unroll
  for (int d = 1; d < 64; d <<= 1) {
    Xf O = xf_shfl_up(P, d);
    if (lane >= d) P = xf_compose(O, P);
  }

  // ---- exclusive prefix + initial frame ----
  Xf E = xf_shfl_up(P, 1);
  Xf A;
  {
    // Frame of (N_INIT, CA_INIT, C_INIT); all-constant, folds at compile time.
    const float ax=17.047f, ay=14.099f, az=3.625f;
    const float bx_=16.967f, by_=12.784f, bz_=4.338f;
    const float cx_=15.685f, cy_=12.755f, cz_=5.133f;
    float abx=bx_-ax, aby=by_-ay, abz=bz_-az;
    float vx=cx_-bx_, vy=cy_-by_, vz=cz_-bz_;
    float vn = sqrtf(vx*vx+vy*vy+vz*vz) + 1e-8f;
    vx/=vn; vy/=vn; vz/=vn;
    float crx = aby*vz - abz*vy;
    float cry = abz*vx - abx*vz;
    float crz = abx*vy - aby*vx;
    float cn = sqrtf(crx*crx+cry*cry+crz*crz) + 1e-8f;
    float nx=crx/cn, ny=cry/cn, nz=crz/cn;
    float mx = ny*vz - nz*vy;
    float my = nz*vx - nx*vz;
    float mz = nx*vy - ny*vx;
    Xf I0;
    I0.r[0]=vx; I0.r[1]=mx; I0.r[2]=nx;
    I0.r[3]=vy; I0.r[4]=my; I0.r[5]=ny;
    I0.r[6]=vz; I0.r[7]=mz; I0.r[8]=nz;
    I0.t[0]=cx_; I0.t[1]=cy_; I0.t[2]=cz_;
    A = (lane == 0) ? I0 : xf_compose(I0, E);
  }

  // ---- Phase C: replay with global prefix, write positions ----
  float* orow = g_out + (size_t)chain * (3*LCH) * 3;
  if (lane < 9) orow[lane] = c_init[lane];

#pragma unroll
  for (int e = 0; e < RPL; ++e) {
    int j = j0 + e;
    if (j < NRES) {
      float* o = orow + (size_t)(3 + 3*j) * 3;
      xf_step(A, ba_[3*e+1], bl_[3*e+2], psi_[e]);
      o[0]=A.t[0]; o[1]=A.t[1]; o[2]=A.t[2];
      xf_step(A, ba_[3*e+2], bl_[3*e+0], omg_[e]);
      o[3]=A.t[0]; o[4]=A.t[1]; o[5]=A.t[2];
      xf_step(A, ba_[3*e+0], bl_[3*e+1], phiN[e]);
      o[6]=A.t[0]; o[7]=A.t[1]; o[8]=A.t[2];
    }
  }
}

extern "C" void kernel_launch(void* const* d_in, const int* in_sizes, int n_in,
                              void* d_out, int out_size, void* d_ws, size_t ws_size,
                              hipStream_t stream) {
  const float* phi = (const float*)d_in[0];
  const float* psi = (const float*)d_in[1];
  const float* omg = (const float*)d_in[2];
  const float* bl  = (const float*)d_in[3];
  const float* ba  = (const float*)d_in[4];
  float* out = (float*)d_out;
  const int B = in_sizes[0] / LCH;          // 4096 chains
  hipLaunchKernelGGL(nerf_wavescan_kernel, dim3(B / 4), dim3(256), 0, stream,
                     phi, psi, omg, bl, ba, out);
}

// Round 3
// 167.069 us; speedup vs baseline: 1.0263x; 1.0263x over previous
//
#include <hip/hip_runtime.h>
#include <math.h>

// Parallel NeRF via wave-level scan of rigid transforms.
// One 64-lane wave per chain (4 chains / 256-thread block). Ownership is
// retiled so each lane produces EXACTLY 72 contiguous chain floats:
//   lane 0   : init triple (9 floats) + residues 0..6        -> floats [0,72)
//   lane l>=1: residues 8l-1 .. 8l+6 (8 residues, 24 atoms)  -> floats [72l,72l+72)
// Phase A: serial delta product per lane; Phase B: shfl-up inclusive scan
// (6 levels); Phase C: replay with exclusive prefix, stage positions in LDS
// (per-lane stride 73 dwords -> conflict-free), then fully-coalesced
// global_store_dwordx4 epilogue (fixes the 64-lines-per-store-inst disaster
// that pinned rounds 1-2 at ~73 us).

#define LCH 512
#define NRES 511

struct Xf { float r[9]; float t[3]; };

__device__ __forceinline__ Xf xf_compose(const Xf& A, const Xf& B) {
  Xf C;
#pragma unroll
  for (int i = 0; i < 3; ++i) {
    float a0 = A.r[3*i+0], a1 = A.r[3*i+1], a2 = A.r[3*i+2];
    C.r[3*i+0] = a0*B.r[0] + a1*B.r[3] + a2*B.r[6];
    C.r[3*i+1] = a0*B.r[1] + a1*B.r[4] + a2*B.r[7];
    C.r[3*i+2] = a0*B.r[2] + a1*B.r[5] + a2*B.r[8];
    C.t[i]     = a0*B.t[0] + a1*B.t[1] + a2*B.t[2] + A.t[i];
  }
  return C;
}

// P := P o Delta(theta, len, tau), sparsity-aware (~31 FMA).
__device__ __forceinline__ void xf_step(Xf& P, float theta, float len, float tau) {
  float st, ct, sx, cx;
  __sincosf(theta, &st, &ct);
  __sincosf(tau, &sx, &cx);
  float ux = -ct, uy = cx*st, uz = sx*st;      // delta col0 (= d_local / L)
  float v0 = -st, v1 = -ct*cx, v2 = -ct*sx;    // delta col1
  float c00 = P.r[0]*ux + P.r[1]*uy + P.r[2]*uz;
  float c10 = P.r[3]*ux + P.r[4]*uy + P.r[5]*uz;
  float c20 = P.r[6]*ux + P.r[7]*uy + P.r[8]*uz;
  float c01 = P.r[0]*v0 + P.r[1]*v1 + P.r[2]*v2;
  float c11 = P.r[3]*v0 + P.r[4]*v1 + P.r[5]*v2;
  float c21 = P.r[6]*v0 + P.r[7]*v1 + P.r[8]*v2;
  float c02 = P.r[2]*cx - P.r[1]*sx;
  float c12 = P.r[5]*cx - P.r[4]*sx;
  float c22 = P.r[8]*cx - P.r[7]*sx;
  P.t[0] += len*c00; P.t[1] += len*c10; P.t[2] += len*c20;
  P.r[0]=c00; P.r[1]=c01; P.r[2]=c02;
  P.r[3]=c10; P.r[4]=c11; P.r[5]=c12;
  P.r[6]=c20; P.r[7]=c21; P.r[8]=c22;
}

__device__ __forceinline__ void xf_set_delta(Xf& P, float theta, float len, float tau) {
  float st, ct, sx, cx;
  __sincosf(theta, &st, &ct);
  __sincosf(tau, &sx, &cx);
  float ux = -ct, uy = cx*st, uz = sx*st;
  P.r[0]=ux; P.r[1]=-st;    P.r[2]=0.f;
  P.r[3]=uy; P.r[4]=-ct*cx; P.r[5]=-sx;
  P.r[6]=uz; P.r[7]=-ct*sx; P.r[8]=cx;
  P.t[0]=len*ux; P.t[1]=len*uy; P.t[2]=len*uz;
}

__device__ __forceinline__ void xf_identity(Xf& A) {
  A.r[0]=1.f; A.r[1]=0.f; A.r[2]=0.f;
  A.r[3]=0.f; A.r[4]=1.f; A.r[5]=0.f;
  A.r[6]=0.f; A.r[7]=0.f; A.r[8]=1.f;
  A.t[0]=0.f; A.t[1]=0.f; A.t[2]=0.f;
}

__device__ __forceinline__ Xf xf_shfl_up(const Xf& P, int d) {
  Xf O;
#pragma unroll
  for (int i = 0; i < 9; ++i) O.r[i] = __shfl_up(P.r[i], d, 64);
#pragma unroll
  for (int i = 0; i < 3; ++i) O.t[i] = __shfl_up(P.t[i], d, 64);
  return O;
}

#define LSTRIDE 73   // per-lane LDS region stride (dwords); 73 mod 32 = 9, coprime

__global__ __launch_bounds__(256) void nerf_wavescan_kernel(
    const float* __restrict__ g_phi, const float* __restrict__ g_psi,
    const float* __restrict__ g_omg, const float* __restrict__ g_bl,
    const float* __restrict__ g_ba, float* __restrict__ g_out)
{
  __shared__ float S[4][LSTRIDE * 64];

  const int lane  = threadIdx.x & 63;
  const int wave  = threadIdx.x >> 6;
  const int chain = blockIdx.x * 4 + wave;
  float* sw = &S[wave][0];

  const float* phir = g_phi + (size_t)chain * LCH;
  const float* psir = g_psi + (size_t)chain * LCH;
  const float* omgr = g_omg + (size_t)chain * LCH;
  const float* blr  = g_bl  + (size_t)chain * LCH * 3;
  const float* bar  = g_ba  + (size_t)chain * LCH * 3;

  const int j0 = lane * 8;  // first LOADED residue (aligned)

  // ---- vectorized aligned loads of residues 8l..8l+7 ----
  float psi_[8], omg_[8], phl_[8], bl_[24], ba_[24];
  {
    const float4* p;
    p = (const float4*)(psir + j0);
#pragma unroll
    for (int q = 0; q < 2; ++q) { float4 v = p[q];
      psi_[4*q]=v.x; psi_[4*q+1]=v.y; psi_[4*q+2]=v.z; psi_[4*q+3]=v.w; }
    p = (const float4*)(omgr + j0);
#pragma unroll
    for (int q = 0; q < 2; ++q) { float4 v = p[q];
      omg_[4*q]=v.x; omg_[4*q+1]=v.y; omg_[4*q+2]=v.z; omg_[4*q+3]=v.w; }
    p = (const float4*)(phir + j0);
#pragma unroll
    for (int q = 0; q < 2; ++q) { float4 v = p[q];
      phl_[4*q]=v.x; phl_[4*q+1]=v.y; phl_[4*q+2]=v.z; phl_[4*q+3]=v.w; }
    p = (const float4*)(blr + (size_t)j0*3);
#pragma unroll
    for (int q = 0; q < 6; ++q) { float4 v = p[q];
      bl_[4*q]=v.x; bl_[4*q+1]=v.y; bl_[4*q+2]=v.z; bl_[4*q+3]=v.w; }
    p = (const float4*)(bar + (size_t)j0*3);
#pragma unroll
    for (int q = 0; q < 6; ++q) { float4 v = p[q];
      ba_[4*q]=v.x; ba_[4*q+1]=v.y; ba_[4*q+2]=v.z; ba_[4*q+3]=v.w; }
  }

  // params of residue 8l-1 (lane l-1's loaded slot 7); lane 0 gets finite junk
  float psip = __shfl_up(psi_[7], 1, 64);
  float omgp = __shfl_up(omg_[7], 1, 64);
  float pbl0 = __shfl_up(bl_[21], 1, 64);
  float pbl1 = __shfl_up(bl_[22], 1, 64);
  float pbl2 = __shfl_up(bl_[23], 1, 64);
  float pba0 = __shfl_up(ba_[21], 1, 64);
  float pba1 = __shfl_up(ba_[22], 1, 64);
  float pba2 = __shfl_up(ba_[23], 1, 64);

  // ---- Phase A: serial product over owned residues ----
  Xf P;
  // residue 8l-1 (junk for lane 0, reset below)
  xf_set_delta(P, pba1, pbl2, psip);            // N : theta=ba[j][1] L=bl[j][2] tau=psi[j]
  xf_step(P, pba2, pbl0, omgp);                 // CA: theta=ba[j][2] L=bl[j][0] tau=omega[j]
  xf_step(P, pba0, pbl1, phl_[0]);              // C : theta=ba[j][0] L=bl[j][1] tau=phi[j+1]=phi[8l]
  if (lane == 0) xf_identity(P);
  // own residues 8l+e, e=0..6
#pragma unroll
  for (int e = 0; e < 7; ++e) {
    xf_step(P, ba_[3*e+1], bl_[3*e+2], psi_[e]);
    xf_step(P, ba_[3*e+2], bl_[3*e+0], omg_[e]);
    xf_step(P, ba_[3*e+0], bl_[3*e+1], phl_[e+1]);
  }

  // ---- Phase B: wave inclusive scan (non-commutative, earlier on left) ----
#pragma unroll
  for (int d = 1; d < 64; d <<= 1) {
    Xf O = xf_shfl_up(P, d);
    if (lane >= d) P = xf_compose(O, P);
  }

  // ---- exclusive prefix composed with the constant initial frame ----
  Xf E = xf_shfl_up(P, 1);
  Xf A;
  {
    const float ax=17.047f, ay=14.099f, az=3.625f;
    const float bx_=16.967f, by_=12.784f, bz_=4.338f;
    const float cx_=15.685f, cy_=12.755f, cz_=5.133f;
    float abx=bx_-ax, aby=by_-ay, abz=bz_-az;
    float vx=cx_-bx_, vy=cy_-by_, vz=cz_-bz_;
    float vn = sqrtf(vx*vx+vy*vy+vz*vz) + 1e-8f;
    vx/=vn; vy/=vn; vz/=vn;
    float crx = aby*vz - abz*vy;
    float cry = abz*vx - abx*vz;
    float crz = abx*vy - aby*vx;
    float cn = sqrtf(crx*crx+cry*cry+crz*crz) + 1e-8f;
    float nx=crx/cn, ny=cry/cn, nz=crz/cn;
    float mx = ny*vz - nz*vy;
    float my = nz*vx - nx*vz;
    float mz = nx*vy - ny*vx;
    Xf I0;
    I0.r[0]=vx; I0.r[1]=mx; I0.r[2]=nx;
    I0.r[3]=vy; I0.r[4]=my; I0.r[5]=ny;
    I0.r[6]=vz; I0.r[7]=mz; I0.r[8]=nz;
    I0.t[0]=cx_; I0.t[1]=cy_; I0.t[2]=cz_;
    A = (lane == 0) ? I0 : xf_compose(I0, E);
  }

  // ---- Phase C: replay, staging 72 floats/lane into LDS (stride 73) ----
  float* reg = sw + LSTRIDE * lane;
  if (lane != 0) {
    xf_step(A, pba1, pbl2, psip);
    reg[0]=A.t[0]; reg[1]=A.t[1]; reg[2]=A.t[2];
    xf_step(A, pba2, pbl0, omgp);
    reg[3]=A.t[0]; reg[4]=A.t[1]; reg[5]=A.t[2];
    xf_step(A, pba0, pbl1, phl_[0]);
    reg[6]=A.t[0]; reg[7]=A.t[1]; reg[8]=A.t[2];
  } else {
    reg[0]=17.047f; reg[1]=14.099f; reg[2]=3.625f;
    reg[3]=16.967f; reg[4]=12.784f; reg[5]=4.338f;
    reg[6]=15.685f; reg[7]=12.755f; reg[8]=5.133f;
  }
#pragma unroll
  for (int e = 0; e < 7; ++e) {
    float* o = reg + 9 + 9*e;
    xf_step(A, ba_[3*e+1], bl_[3*e+2], psi_[e]);
    o[0]=A.t[0]; o[1]=A.t[1]; o[2]=A.t[2];
    xf_step(A, ba_[3*e+2], bl_[3*e+0], omg_[e]);
    o[3]=A.t[0]; o[4]=A.t[1]; o[5]=A.t[2];
    xf_step(A, ba_[3*e+0], bl_[3*e+1], phl_[e+1]);
    o[6]=A.t[0]; o[7]=A.t[1]; o[8]=A.t[2];
  }

  // ---- Epilogue: coalesced dwordx4 stores (wave-local LDS, no barrier) ----
  // global float g = 4*lane + 256*q; owner lo = g/72, f = g%72 (never crosses
  // a 72-float region since 72 % 4 == 0); LDS dword addr = 73*lo + f.
  float* orow = g_out + (size_t)chain * (3 * LCH) * 3;
  int g0 = 4 * lane;
  int lo = g0 / 72;
  int f  = g0 - 72 * lo;
  int addr = LSTRIDE * lo + f;
#pragma unroll
  for (int q = 0; q < 18; ++q) {
    float4 v;
    v.x = sw[addr]; v.y = sw[addr+1]; v.z = sw[addr+2]; v.w = sw[addr+3];
    *(float4*)(orow + 4*lane + 256*q) = v;
    // g += 256 = 3*72 + 40  ->  f += 40 (one possible wrap), addr += 259/260
    f += 40;
    int wrap = (f >= 72) ? 1 : 0;
    f -= 72 * wrap;
    addr += 259 + wrap;
  }
}

extern "C" void kernel_launch(void* const* d_in, const int* in_sizes, int n_in,
                              void* d_out, int out_size, void* d_ws, size_t ws_size,
                              hipStream_t stream) {
  const float* phi = (const float*)d_in[0];
  const float* psi = (const float*)d_in[1];
  const float* omg = (const float*)d_in[2];
  const float* bl  = (const float*)d_in[3];
  const float* ba  = (const float*)d_in[4];
  float* out = (float*)d_out;
  const int B = in_sizes[0] / LCH;          // 4096 chains
  hipLaunchKernelGGL(nerf_wavescan_kernel, dim3(B / 4), dim3(256), 0, stream,
                     phi, psi, omg, bl, ba, out);
}

// Round 7
// 146.116 us; speedup vs baseline: 1.1735x; 1.1434x over previous
//
#include <hip/hip_runtime.h>
#include <math.h>

// Parallel NeRF via rigid-transform scan. Round 6: R4 architecture with
// defensive structural simplifications (R4/R5 submissions hit repeated
// "container failed" infra errors; source changed to dodge any toxic
// construct while preserving the design).
//
// Block (256 threads) = one chain. Thread t owns 2 residues (6 atoms, 18
// output floats): thread 0 -> init triple + residue 0; thread t>=1 ->
// residues 2t-1, 2t. Phases: direct global loads (18 params/thread) ->
// 6-step serial delta product -> intra-wave shfl scan (6 levels) ->
// cross-wave fixup via 4 wave-totals in LDS (1 barrier, unrolled uniform
// composes) -> replay + LDS output staging -> coalesced float2 sweep.

#define LCH 512

struct Xf { float r[9]; float t[3]; };

__device__ __forceinline__ Xf xf_compose(const Xf& A, const Xf& B) {
  Xf C;
#pragma unroll
  for (int i = 0; i < 3; ++i) {
    float a0 = A.r[3*i+0], a1 = A.r[3*i+1], a2 = A.r[3*i+2];
    C.r[3*i+0] = a0*B.r[0] + a1*B.r[3] + a2*B.r[6];
    C.r[3*i+1] = a0*B.r[1] + a1*B.r[4] + a2*B.r[7];
    C.r[3*i+2] = a0*B.r[2] + a1*B.r[5] + a2*B.r[8];
    C.t[i]     = a0*B.t[0] + a1*B.t[1] + a2*B.t[2] + A.t[i];
  }
  return C;
}

// P := P o Delta(theta, len, tau), sparsity-aware (~31 FMA).
__device__ __forceinline__ void xf_step(Xf& P, float theta, float len, float tau) {
  float st, ct, sx, cx;
  __sincosf(theta, &st, &ct);
  __sincosf(tau, &sx, &cx);
  float ux = -ct, uy = cx*st, uz = sx*st;      // delta col0 (= d_local / L)
  float v0 = -st, v1 = -ct*cx, v2 = -ct*sx;    // delta col1; col2 = (0,-sx,cx)
  float c00 = P.r[0]*ux + P.r[1]*uy + P.r[2]*uz;
  float c10 = P.r[3]*ux + P.r[4]*uy + P.r[5]*uz;
  float c20 = P.r[6]*ux + P.r[7]*uy + P.r[8]*uz;
  float c01 = P.r[0]*v0 + P.r[1]*v1 + P.r[2]*v2;
  float c11 = P.r[3]*v0 + P.r[4]*v1 + P.r[5]*v2;
  float c21 = P.r[6]*v0 + P.r[7]*v1 + P.r[8]*v2;
  float c02 = P.r[2]*cx - P.r[1]*sx;
  float c12 = P.r[5]*cx - P.r[4]*sx;
  float c22 = P.r[8]*cx - P.r[7]*sx;
  P.t[0] += len*c00; P.t[1] += len*c10; P.t[2] += len*c20;
  P.r[0]=c00; P.r[1]=c01; P.r[2]=c02;
  P.r[3]=c10; P.r[4]=c11; P.r[5]=c12;
  P.r[6]=c20; P.r[7]=c21; P.r[8]=c22;
}

__device__ __forceinline__ void xf_set_delta(Xf& P, float theta, float len, float tau) {
  float st, ct, sx, cx;
  __sincosf(theta, &st, &ct);
  __sincosf(tau, &sx, &cx);
  float ux = -ct, uy = cx*st, uz = sx*st;
  P.r[0]=ux; P.r[1]=-st;    P.r[2]=0.f;
  P.r[3]=uy; P.r[4]=-ct*cx; P.r[5]=-sx;
  P.r[6]=uz; P.r[7]=-ct*sx; P.r[8]=cx;
  P.t[0]=len*ux; P.t[1]=len*uy; P.t[2]=len*uz;
}

__device__ __forceinline__ void xf_identity(Xf& A) {
  A.r[0]=1.f; A.r[1]=0.f; A.r[2]=0.f;
  A.r[3]=0.f; A.r[4]=1.f; A.r[5]=0.f;
  A.r[6]=0.f; A.r[7]=0.f; A.r[8]=1.f;
  A.t[0]=0.f; A.t[1]=0.f; A.t[2]=0.f;
}

__device__ __forceinline__ Xf xf_shfl_up(const Xf& P, int d) {
  Xf O;
#pragma unroll
  for (int i = 0; i < 9; ++i) O.r[i] = __shfl_up(P.r[i], d, 64);
#pragma unroll
  for (int i = 0; i < 3; ++i) O.t[i] = __shfl_up(P.t[i], d, 64);
  return O;
}

__device__ __forceinline__ void xf_load_lds(const float* p, Xf& A) {
#pragma unroll
  for (int i = 0; i < 9; ++i) A.r[i] = p[i];
#pragma unroll
  for (int i = 0; i < 3; ++i) A.t[i] = p[9+i];
}

__global__ __launch_bounds__(256) void nerf_r6_kernel(
    const float* __restrict__ g_phi, const float* __restrict__ g_psi,
    const float* __restrict__ g_omg, const float* __restrict__ g_bl,
    const float* __restrict__ g_ba, float* __restrict__ g_out)
{
  __shared__ float s_tot[48];                    // 4 wave-totals x 12 floats
  __shared__ float s_out[4608];                  // output staging (18 KB)

  const int t    = threadIdx.x;       // 0..255
  const int lane = t & 63;
  const int wave = t >> 6;
  const int chain = blockIdx.x;

  const float* phir = g_phi + (size_t)chain * LCH;
  const float* psir = g_psi + (size_t)chain * LCH;
  const float* omgr = g_omg + (size_t)chain * LCH;
  const float* blr  = g_bl  + (size_t)chain * LCH * 3;
  const float* bar  = g_ba  + (size_t)chain * LCH * 3;

  // residues: A = 2t-1 (clamped junk for t=0, discarded), B = 2t
  const int jm = (2*t - 1) > 0 ? (2*t - 1) : 0;
  const int jo = 2*t;

  // ---- direct loads: 18 params/thread ----
  float psiA = psir[jm], psiB = psir[jo];
  float omgA = omgr[jm], omgB = omgr[jo];
  float phiA = phir[jo], phiB = phir[jo + 1];  // phi[jm+1], phi[jo+1]
  float blA0 = blr[3*jm+0], blA1 = blr[3*jm+1], blA2 = blr[3*jm+2];
  float blB0 = blr[3*jo+0], blB1 = blr[3*jo+1], blB2 = blr[3*jo+2];
  float baA0 = bar[3*jm+0], baA1 = bar[3*jm+1], baA2 = bar[3*jm+2];
  float baB0 = bar[3*jo+0], baB1 = bar[3*jo+1], baB2 = bar[3*jo+2];

  // ---- Phase A: serial product over owned residues ----
  Xf P;
  xf_set_delta(P, baA1, blA2, psiA);   // N : theta=ba[j][1] L=bl[j][2] tau=psi[j]
  xf_step(P, baA2, blA0, omgA);        // CA: theta=ba[j][2] L=bl[j][0] tau=omega[j]
  xf_step(P, baA0, blA1, phiA);        // C : theta=ba[j][0] L=bl[j][1] tau=phi[j+1]
  if (t == 0) xf_identity(P);
  xf_step(P, baB1, blB2, psiB);
  xf_step(P, baB2, blB0, omgB);
  xf_step(P, baB0, blB1, phiB);

  // ---- Phase B: intra-wave inclusive scan (non-commutative) ----
#pragma unroll
  for (int d = 1; d < 64; d <<= 1) {
    Xf O = xf_shfl_up(P, d);
    if (lane >= d) P = xf_compose(O, P);
  }

  // ---- cross-wave fixup: wave totals through LDS ----
  if (lane == 63) {
#pragma unroll
    for (int i = 0; i < 9; ++i) s_tot[12*wave + i] = P.r[i];
#pragma unroll
    for (int i = 0; i < 3; ++i) s_tot[12*wave + 9 + i] = P.t[i];
  }
  Xf E = xf_shfl_up(P, 1);   // within-wave exclusive (junk for lane 0)
  __syncthreads();

  // A = I0 o T_0 o ... o T_{wave-1} o E_lane (wave-uniform unrolled)
  Xf A;
  {
    const float ax=17.047f, ay=14.099f, az=3.625f;
    const float bx_=16.967f, by_=12.784f, bz_=4.338f;
    const float cx_=15.685f, cy_=12.755f, cz_=5.133f;
    float abx=bx_-ax, aby=by_-ay, abz=bz_-az;
    float vx=cx_-bx_, vy=cy_-by_, vz=cz_-bz_;
    float vn = sqrtf(vx*vx+vy*vy+vz*vz) + 1e-8f;
    vx/=vn; vy/=vn; vz/=vn;
    float crx = aby*vz - abz*vy;
    float cry = abz*vx - abx*vz;
    float crz = abx*vy - aby*vx;
    float cn = sqrtf(crx*crx+cry*cry+crz*crz) + 1e-8f;
    float nx=crx/cn, ny=cry/cn, nz=crz/cn;
    float mx = ny*vz - nz*vy;
    float my = nz*vx - nx*vz;
    float mz = nx*vy - ny*vx;
    A.r[0]=vx; A.r[1]=mx; A.r[2]=nx;
    A.r[3]=vy; A.r[4]=my; A.r[5]=ny;
    A.r[6]=vz; A.r[7]=mz; A.r[8]=nz;
    A.t[0]=cx_; A.t[1]=cy_; A.t[2]=cz_;
  }
  if (wave >= 1) { Xf T; xf_load_lds(&s_tot[0],  T); A = xf_compose(A, T); }
  if (wave >= 2) { Xf T; xf_load_lds(&s_tot[12], T); A = xf_compose(A, T); }
  if (wave >= 3) { Xf T; xf_load_lds(&s_tot[24], T); A = xf_compose(A, T); }
  if (lane > 0) A = xf_compose(A, E);

  // ---- Phase C: replay, stage 18 floats/thread into LDS (plain layout) ----
  float* o = s_out + 18 * t;
  if (t == 0) {
    o[0]=17.047f; o[1]=14.099f; o[2]=3.625f;
    o[3]=16.967f; o[4]=12.784f; o[5]=4.338f;
    o[6]=15.685f; o[7]=12.755f; o[8]=5.133f;
  } else {
    xf_step(A, baA1, blA2, psiA);
    o[0]=A.t[0]; o[1]=A.t[1]; o[2]=A.t[2];
    xf_step(A, baA2, blA0, omgA);
    o[3]=A.t[0]; o[4]=A.t[1]; o[5]=A.t[2];
    xf_step(A, baA0, blA1, phiA);
    o[6]=A.t[0]; o[7]=A.t[1]; o[8]=A.t[2];
  }
  xf_step(A, baB1, blB2, psiB);
  o[9]=A.t[0];  o[10]=A.t[1]; o[11]=A.t[2];
  xf_step(A, baB2, blB0, omgB);
  o[12]=A.t[0]; o[13]=A.t[1]; o[14]=A.t[2];
  xf_step(A, baB0, blB1, phiB);
  o[15]=A.t[0]; o[16]=A.t[1]; o[17]=A.t[2];
  __syncthreads();

  // ---- Epilogue: coalesced float2 sweep (9 x 512B-per-wave rounds) ----
  float* orow = g_out + (size_t)chain * 4608;
#pragma unroll
  for (int q = 0; q < 9; ++q) {
    int g = 2*t + 512*q;
    float x = s_out[g];
    float y = s_out[g + 1];
    orow[g]     = x;
    orow[g + 1] = y;
  }
}

extern "C" void kernel_launch(void* const* d_in, const int* in_sizes, int n_in,
                              void* d_out, int out_size, void* d_ws, size_t ws_size,
                              hipStream_t stream) {
  const float* phi = (const float*)d_in[0];
  const float* psi = (const float*)d_in[1];
  const float* omg = (const float*)d_in[2];
  const float* bl  = (const float*)d_in[3];
  const float* ba  = (const float*)d_in[4];
  float* out = (float*)d_out;
  const int B = in_sizes[0] / LCH;          // 4096 chains
  hipLaunchKernelGGL(nerf_r6_kernel, dim3(B), dim3(256), 0, stream,
                     phi, psi, omg, bl, ba, out);
}